// Round 3
// baseline (631.444 us; speedup 1.0000x reference)
//
#include <hip/hip_runtime.h>
#include <math.h>

// ---------------- compile-time 64-point twiddle tables ----------------
struct cf2 { float x, y; };
struct TW64 { float c[64], s[64]; };
struct CF2T { cf2 v[64]; };

constexpr double PI_D = 3.14159265358979323846264338327950288;

constexpr double tsin(double x){
  double x2 = x*x, r = x, t = x;
  t *= -x2/6.0;   r += t;
  t *= -x2/20.0;  r += t;
  t *= -x2/42.0;  r += t;
  t *= -x2/72.0;  r += t;
  t *= -x2/110.0; r += t;
  t *= -x2/156.0; r += t;
  t *= -x2/210.0; r += t;
  t *= -x2/272.0; r += t;
  return r;
}
constexpr double tcos(double x){
  double x2 = x*x, r = 1.0, t = 1.0;
  t *= -x2/2.0;   r += t;
  t *= -x2/12.0;  r += t;
  t *= -x2/30.0;  r += t;
  t *= -x2/56.0;  r += t;
  t *= -x2/90.0;  r += t;
  t *= -x2/132.0; r += t;
  t *= -x2/182.0; r += t;
  t *= -x2/240.0; r += t;
  return r;
}
constexpr double ang_cos(int j){
  int r = j & 15, q = (j >> 4) & 3;
  double a = PI_D/32.0 * r;
  double cc = tcos(a), ss = tsin(a);
  return q==0 ? cc : q==1 ? -ss : q==2 ? -cc : ss;
}
constexpr double ang_sin(int j){
  int r = j & 15, q = (j >> 4) & 3;
  double a = PI_D/32.0 * r;
  double cc = tcos(a), ss = tsin(a);
  return q==0 ? ss : q==1 ? cc : q==2 ? -ss : -cc;
}
constexpr TW64 make_tw(){
  TW64 t{};
  for (int j=0;j<64;j++){ t.c[j] = (float)ang_cos(j); t.s[j] = (float)ang_sin(j); }
  return t;
}
constexpr CF2T make_twi(){
  CF2T r{};
  for (int j=0;j<64;j++){ r.v[j].x = (float)ang_cos(j); r.v[j].y = (float)ang_sin(j); }
  return r;
}
constexpr CF2T make_pq(){
  CF2T r{};
  for (int j=0;j<64;j++){
    double c = ang_cos(j), s = ang_sin(j);
    r.v[j].x = (float)((c + s) / 262144.0);  // (cos+sin)/64^3
    r.v[j].y = (float)((s - c) / 262144.0);  // (sin-cos)/64^3
  }
  return r;
}

constexpr TW64 TWct = make_tw();        // constant-folded literals (unrolled loops)
__constant__ CF2T TWIdev = make_twi();  // runtime (c,s) lookups
__constant__ CF2T PQdev  = make_pq();   // inverse last-stage coefficients, scale folded

#define NB 512   // persistent grid: 2 blocks/CU guaranteed (LDS 34KB, VGPR<=256)

// ---------------- manual device-scope grid barrier ----------------
// counters zeroed each launch by captured hipMemsetAsync; one counter per barrier.
__device__ __forceinline__ void gridbar(unsigned* bar){
  __syncthreads();
  __threadfence();                 // release: flush this block's global writes
  if (threadIdx.x == 0){
    atomicAdd(bar, 1u);            // device-scope by default on gfx950
    while (__hip_atomic_load(bar, __ATOMIC_ACQUIRE, __HIP_MEMORY_SCOPE_AGENT) < (unsigned)NB)
      __builtin_amdgcn_s_sleep(2);
  }
  __syncthreads();
  __threadfence();                 // acquire for all threads of the block
}

// ---------------- fused kernel LDS ----------------
union SMem {
  struct { float xt[64][64]; float2 y1[8][66]; } s1;                   // 20.1 KB
  struct { float2 yl[64][8]; } s2;                                     // 4 KB
  struct { float wsh[64][64]; float xs[64][64]; float ps[4][64]; } s3; // 33 KB
  struct { float ml[2048]; float2 z1[16][8]; float2 z2[64][8]; } s4;   // 13 KB
};

// stage-A helper: computes k3 = K, K+1 over one xt row (swizzled float4 slots)
template<int K>
__device__ __forceinline__ void stageA2(const float* __restrict__ row, int sw, float* a){
  a[0]=a[1]=a[2]=a[3]=0.f;
  #pragma unroll
  for (int qd=0;qd<16;qd++){
    float4 v = ((const float4*)row)[qd ^ sw];   // swizzled physical slot, logical qd
    float xv[4] = {v.x, v.y, v.z, v.w};
    #pragma unroll
    for (int u=0;u<4;u++){
      int n3 = qd*4 + u;
      a[0] = fmaf(xv[u],  TWct.c[((K  )*n3)&63], a[0]);
      a[1] = fmaf(xv[u], -TWct.s[((K  )*n3)&63], a[1]);
      a[2] = fmaf(xv[u],  TWct.c[((K+1)*n3)&63], a[2]);
      a[3] = fmaf(xv[u], -TWct.s[((K+1)*n3)&63], a[3]);
    }
  }
}

__device__ __forceinline__ void s1_load(const float* __restrict__ x, SMem& sm, int tile, int t){
  const float4* src = (const float4*)(x + (size_t)tile*4096);
  #pragma unroll
  for (int j=0;j<4;j++){
    int q = t + j*256;                  // 0..1023
    float4 v = src[q];
    int n2 = q >> 4, n3q = q & 15;
    float* d = &sm.s1.xt[n2][(n3q ^ (n2 & 7))*4];
    d[0]=v.x; d[1]=v.y; d[2]=v.z; d[3]=v.w;
  }
}

// one kernel: S1 (n3->k3, n2->k2), S2 (n1->k1 + cos_phase),
// S3 (channel mix), S4 (inverse DHT + cos_phase + store), 3 manual grid barriers.
__global__ __launch_bounds__(256, 2) void k_all(
    const float* __restrict__ x,
    const float* __restrict__ w1, const float* __restrict__ w2,
    const float* __restrict__ w3, const float* __restrict__ w4,
    float2* __restrict__ y2g, float* __restrict__ xh, float* __restrict__ cp,
    float* __restrict__ mh, float* __restrict__ out, unsigned* __restrict__ bars)
{
  __shared__ SMem sm;
  __shared__ cf2 twl[64];
  __shared__ cf2 pql[64];
  int t = threadIdx.x;
  int bid = blockIdx.x;
  if (t < 64){ twl[t] = TWIdev.v[t]; pql[t] = PQdev.v[t]; }

  // ================= S1: per (bc,n1) plane, n3->k3 then n2->k2 =================
  // 8192 plane-tiles, 16 per block; load(i+1) overlaps stage B(i)
  {
    int tile0 = bid * 16;
    s1_load(x, sm, tile0, t);
    __syncthreads();
    #pragma unroll 1
    for (int i=0;i<16;i++){
      int tile = tile0 + i;
      {
        int n2 = t & 63, g = t >> 6;        // g uniform per wave
        const float* row = &sm.s1.xt[n2][0];
        int sw = n2 & 7;
        float a[4];
        switch(g){
          case 0: stageA2<0>(row, sw, a); break;
          case 1: stageA2<2>(row, sw, a); break;
          case 2: stageA2<4>(row, sw, a); break;
          default: stageA2<6>(row, sw, a); break;
        }
        sm.s1.y1[2*g  ][n2] = make_float2(a[0], a[1]);
        sm.s1.y1[2*g+1][n2] = make_float2(a[2], a[3]);
      }
      __syncthreads();
      if (i < 15) s1_load(x, sm, tile+1, t);   // writes xt; B reads y1 only
      if (t < 128){
        int k2i = t>>3, k3 = t&7;
        int k2 = k2i<8 ? k2i : 48+k2i;
        cf2 st = twl[k2];
        float c = 1.f, sn = 0.f, ar = 0.f, ai = 0.f;
        const float4* yrow = (const float4*)&sm.s1.y1[k3][0];
        #pragma unroll
        for (int m=0;m<32;m++){
          float4 v = yrow[m];
          ar = fmaf(v.x, c, fmaf(v.y, sn, ar));
          ai = fmaf(v.y, c, fmaf(-v.x, sn, ai));
          float c2 = fmaf(c, st.x, -(sn*st.y));
          float s2 = fmaf(sn, st.x,  c*st.y);
          ar = fmaf(v.z, c2, fmaf(v.w, s2, ar));
          ai = fmaf(v.w, c2, fmaf(-v.z, s2, ai));
          c  = fmaf(c2, st.x, -(s2*st.y));
          sn = fmaf(s2, st.x,  c2*st.y);
        }
        y2g[(size_t)tile*128 + t] = make_float2(ar, ai);
      }
      __syncthreads();
    }
  }
  gridbar(bars + 0);

  // ================= S2: n1->k1, write xh + cos_phase =================
  // 2048 tiles (bc, k2i), 4 per block
  #pragma unroll 1
  for (int i=0;i<4;i++){
    int tile = bid*4 + i;
    int bc = tile >> 4, k2i = tile & 15;
    {
      int n1 = t >> 2, q = t & 3;
      const float4* s4p = (const float4*)(y2g + ((size_t)(bc*64 + n1)*128 + k2i*8));
      ((float4*)&sm.s2.yl[n1][0])[q] = s4p[q];
    }
    __syncthreads();
    {
      int half = t&1, k3 = (t>>1)&7, k1i = t>>4;
      int k1 = k1i<8 ? k1i : 48+k1i;
      cf2 st = twl[k1];
      cf2 cs = twl[(k1*half*32)&63];
      float c = cs.x, sn = cs.y, ar = 0.f, ai = 0.f;
      #pragma unroll
      for (int j=0;j<32;j++){
        float2 y = sm.s2.yl[half*32+j][k3];
        ar = fmaf(y.x, c, fmaf(y.y, sn, ar));
        ai = fmaf(y.y, c, fmaf(-y.x, sn, ai));
        float c2 = fmaf(c, st.x, -(sn*st.y));
        sn = fmaf(sn, st.x,  c*st.y);
        c = c2;
      }
      ar += __shfl_xor(ar, 1, 64);
      ai += __shfl_xor(ai, 1, 64);
      if (half == 0){
        float vxh = ar - ai;                    // Re - Im
        xh[(size_t)(bc*16 + k1i)*128 + k2i*8 + k3] = vxh;
        if (k1i < 8 && k2i < 8){
          cf2 tw = twl[(k1i + k2i + k3) & 63];  // e^{i*2pi*(k1+k2+k3)/64} * conj(X)
          float vxhf = ar*(tw.x - tw.y) + ai*(tw.x + tw.y);
          cp[(size_t)bc*512 + k1i*64 + k2i*8 + k3] = cosf(atan2f(vxhf, vxh));
        }
      }
    }
    __syncthreads();
  }
  gridbar(bars + 1);

  // ================= S3: channel mixing einsum =================
  // 2048 tiles (blk, co, k1l), 4 per block; inner loop over b keeps LDS <= 33 KB
  #pragma unroll 1
  for (int i=0;i<4;i++){
    int tile = bid*4 + i;
    int k1l = tile & 7, co = (tile >> 3) & 63, blk = tile >> 9;
    const float* w = (blk==0) ? w1 : (blk==1) ? w2 : (blk==2) ? w3 : w4;
    int k1i = k1l + ((blk & 1) << 3);
    int k2off = (blk & 2) ? 64 : 0;
    #pragma unroll
    for (int jj=0;jj<4;jj++){
      int idx = t + jj*256;               // 0..1023
      int ci = idx >> 4, kq = idx & 15;
      float4 v = *(const float4*)(w + (size_t)(ci*64 + co)*512 + k1l*64 + kq*4);
      ((float4*)&sm.s3.wsh[ci][0])[kq] = v;
    }
    #pragma unroll 1
    for (int b=0;b<2;b++){
      #pragma unroll
      for (int jj=0;jj<4;jj++){
        int idx = t + jj*256;             // 0..1023
        int ci = idx >> 4, kq = idx & 15;
        float4 v = *(const float4*)(xh + (size_t)((b*64 + ci)*16 + k1i)*128 + k2off + kq*4);
        ((float4*)&sm.s3.xs[ci][0])[kq] = v;
      }
      __syncthreads();
      {
        int quarter = t >> 6, kk = t & 63;
        float acc = 0.f;
        #pragma unroll
        for (int c2=0;c2<16;c2++){
          int ci = quarter*16 + c2;
          acc = fmaf(sm.s3.xs[ci][kk], sm.s3.wsh[ci][kk], acc);
        }
        sm.s3.ps[quarter][kk] = acc;
      }
      __syncthreads();
      if (t < 64)
        mh[(size_t)((b*64 + co)*16 + k1i)*128 + k2off + t] =
          sm.s3.ps[0][t] + sm.s3.ps[1][t] + sm.s3.ps[2][t] + sm.s3.ps[3][t];
      __syncthreads();
    }
  }
  gridbar(bars + 2);

  // ================= S4: inverse DHT (sparse modes) + cos_phase + store =================
  // 8192 tiles (bc, n1), 16 per block; all 16 share bc -> load ml once
  {
    int bc = bid >> 2;
    const float4* srcm = (const float4*)(mh + (size_t)bc * 2048);
    ((float4*)sm.s4.ml)[t]       = srcm[t];
    ((float4*)sm.s4.ml)[t + 256] = srcm[t + 256];
    __syncthreads();
    #pragma unroll 1
    for (int i=0;i<16;i++){
      int n1 = (bid & 3)*16 + i;
      // k1 -> n1 (this tile's n1 only)
      if (t < 128){
        float zr = 0.f, zi = 0.f;
        #pragma unroll
        for (int k1i=0;k1i<16;k1i++){
          int k1 = k1i < 8 ? k1i : 48 + k1i;
          cf2 tw = TWIdev.v[(k1*n1)&63];   // uniform -> s_load
          float m = sm.s4.ml[k1i*128 + t];
          zr = fmaf(m, tw.x, zr);
          zi = fmaf(m, -tw.y, zi);
        }
        sm.s4.z1[t>>3][t&7] = make_float2(zr, zi);
      }
      __syncthreads();
      // k2 -> n2 via rotation recurrence (two chains: k2=0..7 and k2=56..63)
      #pragma unroll
      for (int jo=0;jo<2;jo++){
        int o = t + jo*256;
        int n2 = o >> 3, k3 = o & 7;
        cf2 st = twl[n2];
        float zr = 0.f, zi = 0.f;
        float c = 1.f, sn = 0.f;
        #pragma unroll
        for (int k2i=0;k2i<8;k2i++){
          float2 z = sm.s4.z1[k2i][k3];
          zr = fmaf(z.x, c, fmaf(z.y, sn, zr));
          zi = fmaf(z.y, c, fmaf(-z.x, sn, zi));
          float c2 = fmaf(c, st.x, -(sn*st.y));
          sn = fmaf(sn, st.x, c*st.y);
          c = c2;
        }
        cf2 cs = twl[(56*n2)&63];
        c = cs.x; sn = cs.y;
        #pragma unroll
        for (int k2i=8;k2i<16;k2i++){
          float2 z = sm.s4.z1[k2i][k3];
          zr = fmaf(z.x, c, fmaf(z.y, sn, zr));
          zi = fmaf(z.y, c, fmaf(-z.x, sn, zi));
          float c2 = fmaf(c, st.x, -(sn*st.y));
          sn = fmaf(sn, st.x, c*st.y);
          c = c2;
        }
        sm.s4.z2[n2][k3] = make_float2(zr, zi);
      }
      __syncthreads();
      // k3 -> n3 (Re - Im folded into p/q with 1/64^3), + cos_phase corner, store
      {
        int n3p = t & 31;
        int wv = t >> 6, g = (t >> 5) & 1;
        int n30 = 2*n3p, n31 = 2*n3p + 1;
        float p0[8], q0[8], p1[8], q1[8];
        #pragma unroll
        for (int k3=0;k3<8;k3++){
          cf2 a = pql[(k3*n30)&63];
          cf2 b = pql[(k3*n31)&63];
          p0[k3] = a.x; q0[k3] = a.y;
          p1[k3] = b.x; q1[k3] = b.y;
        }
        float* orow = out + ((size_t)bc*64 + n1)*4096;
        const float* cprow = cp + (size_t)bc*512 + n1*64;
        bool corner = (n1 < 8) && (n3p < 4);
        #pragma unroll
        for (int j=0;j<8;j++){
          int n2 = wv*16 + 2*j + g;
          const float4* zr4 = (const float4*)&sm.s4.z2[n2][0];
          float4 u0 = zr4[0], u1 = zr4[1], u2 = zr4[2], u3 = zr4[3];
          float v0, v1;
          v0 = fmaf(u0.x, p0[0], u0.y*q0[0]);
          v0 = fmaf(u0.z, p0[1], fmaf(u0.w, q0[1], v0));
          v0 = fmaf(u1.x, p0[2], fmaf(u1.y, q0[2], v0));
          v0 = fmaf(u1.z, p0[3], fmaf(u1.w, q0[3], v0));
          v0 = fmaf(u2.x, p0[4], fmaf(u2.y, q0[4], v0));
          v0 = fmaf(u2.z, p0[5], fmaf(u2.w, q0[5], v0));
          v0 = fmaf(u3.x, p0[6], fmaf(u3.y, q0[6], v0));
          v0 = fmaf(u3.z, p0[7], fmaf(u3.w, q0[7], v0));
          v1 = fmaf(u0.x, p1[0], u0.y*q1[0]);
          v1 = fmaf(u0.z, p1[1], fmaf(u0.w, q1[1], v1));
          v1 = fmaf(u1.x, p1[2], fmaf(u1.y, q1[2], v1));
          v1 = fmaf(u1.z, p1[3], fmaf(u1.w, q1[3], v1));
          v1 = fmaf(u2.x, p1[4], fmaf(u2.y, q1[4], v1));
          v1 = fmaf(u2.z, p1[5], fmaf(u2.w, q1[5], v1));
          v1 = fmaf(u3.x, p1[6], fmaf(u3.y, q1[6], v1));
          v1 = fmaf(u3.z, p1[7], fmaf(u3.w, q1[7], v1));
          if (corner && n2 < 8){
            v0 *= cprow[n2*8 + n30];
            v1 *= cprow[n2*8 + n31];
          }
          ((float2*)orow)[n2*32 + n3p] = make_float2(v0, v1);
        }
      }
      __syncthreads();
    }
  }
}

// ---------------- launch ----------------
extern "C" void kernel_launch(void* const* d_in, const int* in_sizes, int n_in,
                              void* d_out, int out_size, void* d_ws, size_t ws_size,
                              hipStream_t stream) {
  (void)in_sizes; (void)n_in; (void)out_size; (void)ws_size;
  const float* x  = (const float*)d_in[0];
  const float* w1 = (const float*)d_in[1];
  const float* w2 = (const float*)d_in[2];
  const float* w3 = (const float*)d_in[3];
  const float* w4 = (const float*)d_in[4];
  float* out = (float*)d_out;
  char* ws = (char*)d_ws;
  float2*   y2g  = (float2*)ws;                                   // 8 MiB
  float*    xh   = (float*)(ws + (8u<<20));                       // 1 MiB
  float*    cp   = (float*)(ws + (9u<<20));                       // 256 KiB
  float*    mh   = (float*)(ws + (9u<<20) + (256u<<10));          // 1 MiB
  unsigned* bars = (unsigned*)(ws + (10u<<20) + (512u<<10));      // 3 counters

  // zero barrier counters (captured into the graph -> re-zeroed every replay)
  hipMemsetAsync(bars, 0, 3*sizeof(unsigned), stream);

  k_all<<<NB, 256, 0, stream>>>(x, w1, w2, w3, w4, y2g, xh, cp, mh, out, bars);
}

// Round 4
// 288.047 us; speedup vs baseline: 2.1922x; 2.1922x over previous
//
#include <hip/hip_runtime.h>
#include <math.h>

// ---------------- compile-time 64-point twiddle tables ----------------
struct cf2 { float x, y; };
struct TW64 { float c[64], s[64]; };
struct CF2T { cf2 v[64]; };

constexpr double PI_D = 3.14159265358979323846264338327950288;

constexpr double tsin(double x){
  double x2 = x*x, r = x, t = x;
  t *= -x2/6.0;   r += t;
  t *= -x2/20.0;  r += t;
  t *= -x2/42.0;  r += t;
  t *= -x2/72.0;  r += t;
  t *= -x2/110.0; r += t;
  t *= -x2/156.0; r += t;
  t *= -x2/210.0; r += t;
  t *= -x2/272.0; r += t;
  return r;
}
constexpr double tcos(double x){
  double x2 = x*x, r = 1.0, t = 1.0;
  t *= -x2/2.0;   r += t;
  t *= -x2/12.0;  r += t;
  t *= -x2/30.0;  r += t;
  t *= -x2/56.0;  r += t;
  t *= -x2/90.0;  r += t;
  t *= -x2/132.0; r += t;
  t *= -x2/182.0; r += t;
  t *= -x2/240.0; r += t;
  return r;
}
constexpr double ang_cos(int j){
  int r = j & 15, q = (j >> 4) & 3;
  double a = PI_D/32.0 * r;
  double cc = tcos(a), ss = tsin(a);
  return q==0 ? cc : q==1 ? -ss : q==2 ? -cc : ss;
}
constexpr double ang_sin(int j){
  int r = j & 15, q = (j >> 4) & 3;
  double a = PI_D/32.0 * r;
  double cc = tcos(a), ss = tsin(a);
  return q==0 ? ss : q==1 ? cc : q==2 ? -ss : -cc;
}
constexpr TW64 make_tw(){
  TW64 t{};
  for (int j=0;j<64;j++){ t.c[j] = (float)ang_cos(j); t.s[j] = (float)ang_sin(j); }
  return t;
}
constexpr CF2T make_twi(){
  CF2T r{};
  for (int j=0;j<64;j++){ r.v[j].x = (float)ang_cos(j); r.v[j].y = (float)ang_sin(j); }
  return r;
}
constexpr CF2T make_pq(){
  CF2T r{};
  for (int j=0;j<64;j++){
    double c = ang_cos(j), s = ang_sin(j);
    r.v[j].x = (float)((c + s) / 262144.0);  // (cos+sin)/64^3
    r.v[j].y = (float)((s - c) / 262144.0);  // (sin-cos)/64^3
  }
  return r;
}

constexpr TW64 TWct = make_tw();        // constant-folded literals (unrolled loops)
__constant__ CF2T TWIdev = make_twi();  // runtime (c,s) lookups
__constant__ CF2T PQdev  = make_pq();   // inverse last-stage coefficients, scale folded

// ---------------- K1: forward n3->k3 (8 modes) and n2->k2 (16 modes) ----------------
// grid = 8192 (one (bc,n1) plane per block), 256 threads
// LDS ~23 KB -> 7 blocks/CU (87% occupancy cap)
// out: y2g[plane][k2i*8+k3] float2   (8 MiB)

// stage-A helper: computes k3 = K, K+1 over one xt row (swizzled float4 slots)
template<int K>
__device__ __forceinline__ void stageA2(const float* __restrict__ row, int sw, float* a){
  a[0]=a[1]=a[2]=a[3]=0.f;
  #pragma unroll
  for (int qd=0;qd<16;qd++){
    float4 v = ((const float4*)row)[qd ^ sw];   // swizzled physical slot, logical qd
    float xv[4] = {v.x, v.y, v.z, v.w};
    #pragma unroll
    for (int u=0;u<4;u++){
      int n3 = qd*4 + u;
      a[0] = fmaf(xv[u],  TWct.c[((K  )*n3)&63], a[0]);
      a[1] = fmaf(xv[u], -TWct.s[((K  )*n3)&63], a[1]);
      a[2] = fmaf(xv[u],  TWct.c[((K+1)*n3)&63], a[2]);
      a[3] = fmaf(xv[u], -TWct.s[((K+1)*n3)&63], a[3]);
    }
  }
}

__global__ __launch_bounds__(256) void k_fwd(const float* __restrict__ x, float2* __restrict__ y2g){
  __shared__ alignas(16) float xt[64][64];    // [n2][swizzled n3] 16 KB
  __shared__ alignas(16) float2 y1[8][66];    // [k3][n2] 4.2 KB
  __shared__ float2 ps[2][128];               // stage-B partials 2 KB
  __shared__ cf2 twl[64];
  int bid = blockIdx.x;                       // plane = bc*64 + n1
  int t = threadIdx.x;
  if (t < 64) twl[t] = TWIdev.v[t];

  // coalesced staging: 16 KB plane, swizzled LDS writes
  const float4* src = (const float4*)(x + (size_t)bid*4096);
  #pragma unroll
  for (int j=0;j<4;j++){
    int q = t + j*256;                  // 0..1023
    float4 v = src[q];
    int n2 = q >> 4, n3q = q & 15;
    float* d = &xt[n2][(n3q ^ (n2 & 7))*4];
    d[0]=v.x; d[1]=v.y; d[2]=v.z; d[3]=v.w;
  }
  __syncthreads();

  // stage A: n3 -> k3; thread (g = t>>6, n2 = t&63) does k3 = 2g, 2g+1
  {
    int n2 = t & 63, g = t >> 6;        // g uniform per wave
    const float* row = &xt[n2][0];
    int sw = n2 & 7;
    float a[4];
    switch(g){
      case 0: stageA2<0>(row, sw, a); break;
      case 1: stageA2<2>(row, sw, a); break;
      case 2: stageA2<4>(row, sw, a); break;
      default: stageA2<6>(row, sw, a); break;
    }
    y1[2*g  ][n2] = make_float2(a[0], a[1]);
    y1[2*g+1][n2] = make_float2(a[2], a[3]);
  }
  __syncthreads();

  // stage B: n2 -> k2. 2 threads per (k2i,k3): thread h handles elements
  // [32h,32h+32) as TWO independent 16-element rotation chains seeded from twl.
  {
    int s = t & 127, h = t >> 7;
    int k2i = s>>3, k3 = s&7;
    int k2 = k2i<8 ? k2i : 48+k2i;
    cf2 st = twl[k2];
    cf2 i0 = twl[(k2*32*h) & 63];            // rotation at element 32h
    cf2 i1 = twl[(k2*(32*h+16)) & 63];       // rotation at element 32h+16
    float c0=i0.x, s0=i0.y, ar0=0.f, ai0=0.f;
    float c1=i1.x, s1=i1.y, ar1=0.f, ai1=0.f;
    const float4* yrow = (const float4*)&y1[k3][0];
    #pragma unroll
    for (int m=0;m<8;m++){
      float4 v = yrow[16*h + m];             // elements 32h+2m, 32h+2m+1
      ar0 = fmaf(v.x, c0, fmaf(v.y, s0, ar0));
      ai0 = fmaf(v.y, c0, fmaf(-v.x, s0, ai0));
      float c0b = fmaf(c0, st.x, -(s0*st.y));
      float s0b = fmaf(s0, st.x,  c0*st.y);
      ar0 = fmaf(v.z, c0b, fmaf(v.w, s0b, ar0));
      ai0 = fmaf(v.w, c0b, fmaf(-v.z, s0b, ai0));
      c0  = fmaf(c0b, st.x, -(s0b*st.y));
      s0  = fmaf(s0b, st.x,  c0b*st.y);

      float4 w = yrow[16*h + 8 + m];         // elements 32h+16+2m, +1
      ar1 = fmaf(w.x, c1, fmaf(w.y, s1, ar1));
      ai1 = fmaf(w.y, c1, fmaf(-w.x, s1, ai1));
      float c1b = fmaf(c1, st.x, -(s1*st.y));
      float s1b = fmaf(s1, st.x,  c1*st.y);
      ar1 = fmaf(w.z, c1b, fmaf(w.w, s1b, ar1));
      ai1 = fmaf(w.w, c1b, fmaf(-w.z, s1b, ai1));
      c1  = fmaf(c1b, st.x, -(s1b*st.y));
      s1  = fmaf(s1b, st.x,  c1b*st.y);
    }
    ps[h][s] = make_float2(ar0+ar1, ai0+ai1);
  }
  __syncthreads();
  if (t < 128){
    float2 a = ps[0][t], b = ps[1][t];
    y2g[(size_t)bid*128 + t] = make_float2(a.x+b.x, a.y+b.y);
  }
}

// ---------------- K2: forward n1->k1 (16 modes) + xh + cos_phase ----------------
// grid = bc*16 + k2i (2048 blocks), 256 threads; per-thread 2 independent chains
__global__ __launch_bounds__(256) void k_fwd_n1(const float2* __restrict__ y2g,
                                                float* __restrict__ xh, float* __restrict__ cp){
  __shared__ alignas(16) float2 yl[64][8];   // [n1][k3] 4 KB
  __shared__ cf2 twl[64];
  int bc = blockIdx.x >> 4, k2i = blockIdx.x & 15;
  int t = threadIdx.x;
  if (t < 64) twl[t] = TWIdev.v[t];
  {
    int n1 = t >> 2, q = t & 3;
    const float4* s4 = (const float4*)(y2g + ((size_t)(bc*64 + n1)*128 + k2i*8));
    ((float4*)&yl[n1][0])[q] = s4[q];
  }
  __syncthreads();
  int half = t&1, k3 = (t>>1)&7, k1i = t>>4;
  int k1 = k1i<8 ? k1i : 48+k1i;
  cf2 st = twl[k1];
  cf2 i0 = twl[(k1*32*half)&63];             // rotation at element 32*half
  cf2 i1 = twl[(k1*(32*half+16))&63];        // rotation at element 32*half+16
  float c0=i0.x, s0=i0.y, ar0=0.f, ai0=0.f;
  float c1=i1.x, s1=i1.y, ar1=0.f, ai1=0.f;
  #pragma unroll
  for (int j=0;j<16;j++){
    float2 y = yl[half*32+j][k3];
    ar0 = fmaf(y.x, c0, fmaf(y.y, s0, ar0));
    ai0 = fmaf(y.y, c0, fmaf(-y.x, s0, ai0));
    float c0b = fmaf(c0, st.x, -(s0*st.y));
    s0 = fmaf(s0, st.x,  c0*st.y);
    c0 = c0b;
    float2 z = yl[half*32+16+j][k3];
    ar1 = fmaf(z.x, c1, fmaf(z.y, s1, ar1));
    ai1 = fmaf(z.y, c1, fmaf(-z.x, s1, ai1));
    float c1b = fmaf(c1, st.x, -(s1*st.y));
    s1 = fmaf(s1, st.x,  c1*st.y);
    c1 = c1b;
  }
  float ar = ar0 + ar1, ai = ai0 + ai1;
  ar += __shfl_xor(ar, 1, 64);
  ai += __shfl_xor(ai, 1, 64);
  if (half == 0){
    float vxh = ar - ai;                    // Re - Im
    xh[(size_t)(bc*16 + k1i)*128 + k2i*8 + k3] = vxh;
    if (k1i < 8 && k2i < 8){
      cf2 tw = twl[(k1i + k2i + k3) & 63];  // e^{i*2pi*(k1+k2+k3)/64} * conj(X)
      float vxhf = ar*(tw.x - tw.y) + ai*(tw.x + tw.y);
      cp[(size_t)bc*512 + k1i*64 + k2i*8 + k3] = cosf(atan2f(vxhf, vxh));
    }
  }
}

// ---------------- K3: per-mode channel mixing (einsum bixyz,ioxyz->boxyz) ----------------
// grid = (blk*64+co)*8 + k1l (2048 blocks), 256 threads
// xh (1 MB) is L2-resident -> read directly (coalesced 256B segments), no LDS staging.
// LDS 17 KB -> 8 blocks/CU (100% occupancy)
__global__ __launch_bounds__(256) void k_mix(const float* __restrict__ xh,
    const float* __restrict__ w1, const float* __restrict__ w2,
    const float* __restrict__ w3, const float* __restrict__ w4,
    float* __restrict__ mh){
  __shared__ alignas(16) float wsh[64][64];     // [ci][k2l*8+k3] 16 KB
  __shared__ float ps[4][64];                   // 1 KB
  int bid = blockIdx.x;
  int k1l = bid & 7, co = (bid >> 3) & 63, blk = bid >> 9;
  const float* w = (blk==0) ? w1 : (blk==1) ? w2 : (blk==2) ? w3 : w4;
  int k1i = k1l + ((blk & 1) << 3);
  int k2off = (blk & 2) ? 64 : 0;
  int t = threadIdx.x;
  #pragma unroll
  for (int jj=0;jj<4;jj++){
    int idx = t + jj*256;               // 0..1023
    int ci = idx >> 4, kq = idx & 15;
    float4 v = *(const float4*)(w + (size_t)(ci*64 + co)*512 + k1l*64 + kq*4);
    ((float4*)&wsh[ci][0])[kq] = v;
  }
  __syncthreads();
  int quarter = t >> 6, kk = t & 63;
  #pragma unroll 1
  for (int b=0;b<2;b++){
    // xh[((b*64+ci)*16 + k1i)*128 + k2off + kk], ci = quarter*16 + c2
    const float* xb = xh + ((size_t)(b*64 + quarter*16)*16 + k1i)*128 + k2off + kk;
    float acc = 0.f;
    #pragma unroll
    for (int c2=0;c2<16;c2++){
      acc = fmaf(xb[(size_t)c2*2048], wsh[quarter*16 + c2][kk], acc);
    }
    ps[quarter][kk] = acc;
    __syncthreads();
    if (t < 64)
      mh[(size_t)((b*64 + co)*16 + k1i)*128 + k2off + t] =
        ps[0][t] + ps[1][t] + ps[2][t] + ps[3][t];
    __syncthreads();
  }
}

// ---------------- K4: fused inverse DHT (sparse modes) + cos_phase + store ----------------
// grid = (b*64+co)*64 + n1 (8192 blocks), 256 threads
// k2->n2 recurrences split into two INDEPENDENT chains (separate accumulators).
__global__ __launch_bounds__(256) void k_inv(const float* __restrict__ mh,
                                             const float* __restrict__ cp,
                                             float* __restrict__ out){
  __shared__ alignas(16) float ml[2048];
  __shared__ alignas(16) float2 z1[16][8];
  __shared__ alignas(16) float2 z2[64][8];
  __shared__ cf2 twl[64];
  __shared__ cf2 pql[64];
  int bid = blockIdx.x;
  int n1 = bid & 63, bc = bid >> 6;
  int t = threadIdx.x;
  if (t < 64){ twl[t] = TWIdev.v[t]; pql[t] = PQdev.v[t]; }
  const float4* src = (const float4*)(mh + (size_t)bc * 2048);
  ((float4*)ml)[t]       = src[t];
  ((float4*)ml)[t + 256] = src[t + 256];
  __syncthreads();
  // k1 -> n1 (this block's n1 only)
  if (t < 128){
    float zr = 0.f, zi = 0.f;
    #pragma unroll
    for (int k1i=0;k1i<16;k1i++){
      int k1 = k1i < 8 ? k1i : 48 + k1i;
      cf2 tw = TWIdev.v[(k1*n1)&63];   // uniform -> s_load
      float m = ml[k1i*128 + t];
      zr = fmaf(m, tw.x, zr);
      zi = fmaf(m, -tw.y, zi);
    }
    z1[t>>3][t&7] = make_float2(zr, zi);
  }
  __syncthreads();
  // k2 -> n2: two independent 8-step chains (k2=0..7 and k2=56..63)
  #pragma unroll
  for (int jo=0;jo<2;jo++){
    int o = t + jo*256;
    int n2 = o >> 3, k3 = o & 7;
    cf2 st = twl[n2];
    float zr0=0.f, zi0=0.f, zr1=0.f, zi1=0.f;
    float c0 = 1.f, s0 = 0.f;
    cf2 i1 = twl[(56*n2)&63];
    float c1 = i1.x, s1 = i1.y;
    #pragma unroll
    for (int k=0;k<8;k++){
      float2 a = z1[k][k3];
      zr0 = fmaf(a.x, c0, fmaf(a.y, s0, zr0));
      zi0 = fmaf(a.y, c0, fmaf(-a.x, s0, zi0));
      float c0b = fmaf(c0, st.x, -(s0*st.y));
      s0 = fmaf(s0, st.x, c0*st.y);
      c0 = c0b;
      float2 b = z1[8+k][k3];
      zr1 = fmaf(b.x, c1, fmaf(b.y, s1, zr1));
      zi1 = fmaf(b.y, c1, fmaf(-b.x, s1, zi1));
      float c1b = fmaf(c1, st.x, -(s1*st.y));
      s1 = fmaf(s1, st.x, c1*st.y);
      c1 = c1b;
    }
    z2[n2][k3] = make_float2(zr0+zr1, zi0+zi1);
  }
  __syncthreads();
  // k3 -> n3 (Re - Im folded into p/q with 1/64^3), + cos_phase corner, store
  {
    int n3p = t & 31;
    int wv = t >> 6, g = (t >> 5) & 1;
    int n30 = 2*n3p, n31 = 2*n3p + 1;
    float p0[8], q0[8], p1[8], q1[8];
    #pragma unroll
    for (int k3=0;k3<8;k3++){
      cf2 a = pql[(k3*n30)&63];
      cf2 b = pql[(k3*n31)&63];
      p0[k3] = a.x; q0[k3] = a.y;
      p1[k3] = b.x; q1[k3] = b.y;
    }
    float* orow = out + ((size_t)bc*64 + n1)*4096;
    const float* cprow = cp + (size_t)bc*512 + n1*64;
    bool corner = (n1 < 8) && (n3p < 4);
    #pragma unroll
    for (int j=0;j<8;j++){
      int n2 = wv*16 + 2*j + g;
      const float4* zr4 = (const float4*)&z2[n2][0];
      float4 u0 = zr4[0], u1 = zr4[1], u2 = zr4[2], u3 = zr4[3];
      float v0, v1;
      v0 = fmaf(u0.x, p0[0], u0.y*q0[0]);
      v0 = fmaf(u0.z, p0[1], fmaf(u0.w, q0[1], v0));
      v0 = fmaf(u1.x, p0[2], fmaf(u1.y, q0[2], v0));
      v0 = fmaf(u1.z, p0[3], fmaf(u1.w, q0[3], v0));
      v0 = fmaf(u2.x, p0[4], fmaf(u2.y, q0[4], v0));
      v0 = fmaf(u2.z, p0[5], fmaf(u2.w, q0[5], v0));
      v0 = fmaf(u3.x, p0[6], fmaf(u3.y, q0[6], v0));
      v0 = fmaf(u3.z, p0[7], fmaf(u3.w, q0[7], v0));
      v1 = fmaf(u0.x, p1[0], u0.y*q1[0]);
      v1 = fmaf(u0.z, p1[1], fmaf(u0.w, q1[1], v1));
      v1 = fmaf(u1.x, p1[2], fmaf(u1.y, q1[2], v1));
      v1 = fmaf(u1.z, p1[3], fmaf(u1.w, q1[3], v1));
      v1 = fmaf(u2.x, p1[4], fmaf(u2.y, q1[4], v1));
      v1 = fmaf(u2.z, p1[5], fmaf(u2.w, q1[5], v1));
      v1 = fmaf(u3.x, p1[6], fmaf(u3.y, q1[6], v1));
      v1 = fmaf(u3.z, p1[7], fmaf(u3.w, q1[7], v1));
      if (corner && n2 < 8){
        v0 *= cprow[n2*8 + n30];
        v1 *= cprow[n2*8 + n31];
      }
      ((float2*)orow)[n2*32 + n3p] = make_float2(v0, v1);
    }
  }
}

// ---------------- launch ----------------
extern "C" void kernel_launch(void* const* d_in, const int* in_sizes, int n_in,
                              void* d_out, int out_size, void* d_ws, size_t ws_size,
                              hipStream_t stream) {
  (void)in_sizes; (void)n_in; (void)out_size; (void)ws_size;
  const float* x  = (const float*)d_in[0];
  const float* w1 = (const float*)d_in[1];
  const float* w2 = (const float*)d_in[2];
  const float* w3 = (const float*)d_in[3];
  const float* w4 = (const float*)d_in[4];
  float* out = (float*)d_out;
  char* ws = (char*)d_ws;
  float2* y2g = (float2*)ws;                                   // 8 MiB
  float*  xh  = (float*)(ws + (8u<<20));                       // 1 MiB
  float*  cp  = (float*)(ws + (9u<<20));                       // 256 KiB
  float*  mh  = (float*)(ws + (9u<<20) + (256u<<10));          // 1 MiB

  k_fwd   <<<8192, 256, 0, stream>>>(x, y2g);
  k_fwd_n1<<<2048, 256, 0, stream>>>(y2g, xh, cp);
  k_mix   <<<2048, 256, 0, stream>>>(xh, w1, w2, w3, w4, mh);
  k_inv   <<<8192, 256, 0, stream>>>(mh, cp, out);
}